// Round 1
// baseline (585.052 us; speedup 1.0000x reference)
//
#include <hip/hip_runtime.h>
#include <hip/hip_bf16.h>

typedef unsigned short ushort_t;
typedef __attribute__((ext_vector_type(4))) float f32x4;
typedef __attribute__((ext_vector_type(8))) short bf16x8;
typedef __attribute__((ext_vector_type(8))) unsigned short us8;

#define T_TOK 4096
#define D_DIM 1024
#define FF_DIM 4096
#define NE 8
#define ESTRIDE 4194304L  // 4096*1024 elements per expert weight matrix

__device__ __forceinline__ unsigned short f2bf(float f) {
  __hip_bfloat16 h = __float2bfloat16(f);
  return __builtin_bit_cast(unsigned short, h);
}
__device__ __forceinline__ float gelu_f(float v) {
  return 0.5f * v * (1.0f + erff(v * 0.70710678118654752440f));
}

// ---------------- gating: logits -> softmax top2 -> expert lists -------------
__global__ void gate_kernel(const float* __restrict__ x, const float* __restrict__ Wg,
                            int* __restrict__ cnt, int* __restrict__ tok,
                            float* __restrict__ wof, int* __restrict__ rankof) {
  const int t = blockIdx.x;
  const int lane = threadIdx.x;  // 64 threads = 1 wave
  const float* xr = x + (long)t * D_DIM;
  float acc[NE];
#pragma unroll
  for (int e = 0; e < NE; e++) acc[e] = 0.f;
#pragma unroll
  for (int i = 0; i < 16; i++) {
    int d = i * 64 + lane;
    float xv = xr[d];
    const float* wr = Wg + d * NE;
#pragma unroll
    for (int e = 0; e < NE; e++) acc[e] += xv * wr[e];
  }
#pragma unroll
  for (int off = 32; off > 0; off >>= 1) {
#pragma unroll
    for (int e = 0; e < NE; e++) acc[e] += __shfl_xor(acc[e], off, 64);
  }
  if (lane == 0) {
    int i0 = 0;
#pragma unroll
    for (int e = 1; e < NE; e++) if (acc[e] > acc[i0]) i0 = e;  // first max (ties -> low idx)
    int i1 = -1;
#pragma unroll
    for (int e = 0; e < NE; e++) {
      if (e == i0) continue;
      if (i1 < 0 || acc[e] > acc[i1]) i1 = e;
    }
    // renormalized top2 softmax weights: w = exp(l_i - l_max) / sum over top2
    float e1 = expf(acc[i1] - acc[i0]);
    float w0 = 1.f / (1.f + e1);
    float w1 = e1 * w0;
    int s0 = atomicAdd(&cnt[i0], 1);
    tok[i0 * T_TOK + s0] = t; wof[i0 * T_TOK + s0] = w0; rankof[i0 * T_TOK + s0] = 0;
    int s1 = atomicAdd(&cnt[i1], 1);
    tok[i1 * T_TOK + s1] = t; wof[i1 * T_TOK + s1] = w1; rankof[i1 * T_TOK + s1] = 1;
    // pseudo-expert 8 = shared FFN, identity routing, weight 1
    tok[8 * T_TOK + t] = t; wof[8 * T_TOK + t] = 1.f; rankof[8 * T_TOK + t] = 0;
  }
}

__global__ void scan_kernel(int* cnt, int* base) {
  if (threadIdx.x == 0 && blockIdx.x == 0) {
    int s = 0;
    for (int e = 0; e < NE; e++) { base[e] = s; s += cnt[e]; }
    base[8] = s;      // always 8192
    cnt[8] = T_TOK;   // shared pseudo-expert gets all tokens
  }
}

// ---------------- fp32 -> bf16 convert (x) ----------------------------------
__global__ void cvt_x_kernel(const float* __restrict__ src, ushort_t* __restrict__ dst) {
  long i = ((long)blockIdx.x * 256 + threadIdx.x) * 8;
  float4 v0 = *(const float4*)(src + i);
  float4 v1 = *(const float4*)(src + i + 4);
  us8 o;
  o[0] = f2bf(v0.x); o[1] = f2bf(v0.y); o[2] = f2bf(v0.z); o[3] = f2bf(v0.w);
  o[4] = f2bf(v1.x); o[5] = f2bf(v1.y); o[6] = f2bf(v1.z); o[7] = f2bf(v1.w);
  *(us8*)(dst + i) = o;
}

// ---------------- fp32 [R][C] -> bf16 [C][R] transpose-convert --------------
__global__ void tcvt_kernel(const float* __restrict__ src, ushort_t* __restrict__ dst,
                            int R, int C) {
  src += (long)blockIdx.z * R * C;
  dst += (long)blockIdx.z * R * C;
  const int r0 = blockIdx.y * 64, c0 = blockIdx.x * 64;
  __shared__ ushort_t tile[64][72];  // +8 pad keeps 16B-aligned rows, breaks bank aliasing
  const int t = threadIdx.x;
#pragma unroll
  for (int i = 0; i < 4; i++) {
    int lin = t + i * 256;
    int r = lin >> 4;
    int c = (lin & 15) * 4;
    float4 v = *(const float4*)(src + (long)(r0 + r) * C + c0 + c);
    tile[c + 0][r] = f2bf(v.x);
    tile[c + 1][r] = f2bf(v.y);
    tile[c + 2][r] = f2bf(v.z);
    tile[c + 3][r] = f2bf(v.w);
  }
  __syncthreads();
#pragma unroll
  for (int i = 0; i < 2; i++) {
    int lin = t + i * 256;
    int cc = lin >> 3, rp = lin & 7;
    us8 v = *(const us8*)&tile[cc][rp * 8];
    *(us8*)(dst + (long)(c0 + cc) * R + r0 + rp * 8) = v;
  }
}

// ---------------- GEMM: 128x128 tile, 4 waves, 16x16x32 bf16 MFMA -----------
// PHASE 1: He[base[e]+r] = gelu( gather(Xbf)[tok] @ W1T[e]^T + b1[e] )   (N=4096,K=1024)
// PHASE 2: e<8: ybuf[rank][t] = w * (He @ W2T[e]^T + b2[e]) ; e==8: out = .. + bs2
template <int K, int N, int PHASE>
__global__ __launch_bounds__(256, 2) void gemm_kernel(
    const ushort_t* __restrict__ Abase, const ushort_t* __restrict__ WT,
    const float* __restrict__ bias_e, const float* __restrict__ bias_s,
    const int* __restrict__ cnt, const int* __restrict__ base,
    const int* __restrict__ tok, const float* __restrict__ wof,
    const int* __restrict__ rankof,
    ushort_t* __restrict__ He, float* __restrict__ ybuf, float* __restrict__ out) {
  const int e = blockIdx.z;
  const int count = cnt[e];
  const int m0 = blockIdx.y * 128;
  if (m0 >= count) return;  // uniform early-exit before any barrier
  const int n0 = blockIdx.x * 128;
  const int tid = threadIdx.x;
  const int w = tid >> 6, lane = tid & 63;

  __shared__ ushort_t sA[128 * 32];
  __shared__ ushort_t sB[128 * 32];

  // each thread stages 2 A-chunks + 2 B-chunks (16B each) per K-step
  const ushort_t* pA[2];
  const ushort_t* pB[2];
#pragma unroll
  for (int j = 0; j < 2; j++) {
    int c = w * 128 + j * 64 + lane;  // chunk id in [0,512)
    int r = c >> 2, kp = c & 3;       // tile row, 8-elem k-part
    int rr = m0 + r;
    int rc = (rr < count) ? rr : 0;   // clamp OOB rows to a safe valid row
    long arow;
    if (PHASE == 1) arow = tok[e * T_TOK + rc];   // gather token row from Xbf
    else            arow = (long)base[e] + rc;    // compacted He row
    pA[j] = Abase + arow * K + kp * 8;
    pB[j] = WT + (long)e * ESTRIDE + (long)(n0 + r) * K + kp * 8;
  }

  f32x4 acc[4][4] = {};
  const int wm = w >> 1, wn = w & 1;
  const int lr = lane & 15, lg = lane >> 4;
  const int lds0 = (w * 128) * 16;        // byte offset of this wave's chunk 0 group
  const int lds1 = (w * 128 + 64) * 16;

  for (int k0 = 0; k0 < K; k0 += 32) {
    __builtin_amdgcn_global_load_lds(
        (const __attribute__((address_space(1))) void*)(pA[0] + k0),
        (__attribute__((address_space(3))) void*)((char*)sA + lds0), 16, 0, 0);
    __builtin_amdgcn_global_load_lds(
        (const __attribute__((address_space(1))) void*)(pA[1] + k0),
        (__attribute__((address_space(3))) void*)((char*)sA + lds1), 16, 0, 0);
    __builtin_amdgcn_global_load_lds(
        (const __attribute__((address_space(1))) void*)(pB[0] + k0),
        (__attribute__((address_space(3))) void*)((char*)sB + lds0), 16, 0, 0);
    __builtin_amdgcn_global_load_lds(
        (const __attribute__((address_space(1))) void*)(pB[1] + k0),
        (__attribute__((address_space(3))) void*)((char*)sB + lds1), 16, 0, 0);
    __syncthreads();  // drains vmcnt then barriers: staging visible to all waves

    bf16x8 av[4], bv[4];
#pragma unroll
    for (int m = 0; m < 4; m++)
      av[m] = *(const bf16x8*)&sA[(wm * 64 + m * 16 + lr) * 32 + lg * 8];
#pragma unroll
    for (int n = 0; n < 4; n++)
      bv[n] = *(const bf16x8*)&sB[(wn * 64 + n * 16 + lr) * 32 + lg * 8];
#pragma unroll
    for (int m = 0; m < 4; m++)
#pragma unroll
      for (int n = 0; n < 4; n++)
        acc[m][n] = __builtin_amdgcn_mfma_f32_16x16x32_bf16(av[m], bv[n], acc[m][n], 0, 0, 0);
    __syncthreads();  // compute done before next stage overwrites LDS
  }

  const float* bias = (e == NE) ? bias_s : (bias_e + (long)e * N);
#pragma unroll
  for (int m = 0; m < 4; m++) {
#pragma unroll
    for (int j = 0; j < 4; j++) {
      int rloc = wm * 64 + m * 16 + lg * 4 + j;  // D row = (lane>>4)*4 + reg (m89-verified)
      int rr = m0 + rloc;
      if (rr >= count) continue;
      if (PHASE == 1) {
        long orow = (long)base[e] + rr;
#pragma unroll
        for (int n = 0; n < 4; n++) {
          int col = n0 + wn * 64 + n * 16 + lr;  // D col = lane&15
          float v = acc[m][n][j] + bias[col];
          He[orow * FF_DIM + col] = f2bf(gelu_f(v));
        }
      } else {
        int tt = tok[e * T_TOK + rr];
        if (e == NE) {  // shared FFN -> write d_out directly (each token once)
#pragma unroll
          for (int n = 0; n < 4; n++) {
            int col = n0 + wn * 64 + n * 16 + lr;
            out[(long)tt * D_DIM + col] = acc[m][n][j] + bias[col];
          }
        } else {
          float wgt = wof[e * T_TOK + rr];
          int rk = rankof[e * T_TOK + rr];
          float* dst = ybuf + (long)rk * ((long)T_TOK * D_DIM) + (long)tt * D_DIM;
#pragma unroll
          for (int n = 0; n < 4; n++) {
            int col = n0 + wn * 64 + n * 16 + lr;
            dst[col] = wgt * (acc[m][n][j] + bias[col]);
          }
        }
      }
    }
  }
}

// ---------------- final: out += y_rank0 + y_rank1 ---------------------------
__global__ void final_add_kernel(float* __restrict__ out, const float* __restrict__ ybuf) {
  long i = ((long)blockIdx.x * 256 + threadIdx.x) * 4;
  float4 a = *(const float4*)(out + i);
  float4 b = *(const float4*)(ybuf + i);
  float4 c = *(const float4*)(ybuf + (long)T_TOK * D_DIM + i);
  a.x += b.x + c.x; a.y += b.y + c.y; a.z += b.z + c.z; a.w += b.w + c.w;
  *(float4*)(out + i) = a;
}

extern "C" void kernel_launch(void* const* d_in, const int* in_sizes, int n_in,
                              void* d_out, int out_size, void* d_ws, size_t ws_size,
                              hipStream_t stream) {
  (void)in_sizes; (void)n_in; (void)out_size; (void)ws_size;
  const float* x   = (const float*)d_in[0];
  const float* Wg  = (const float*)d_in[1];
  const float* W1  = (const float*)d_in[2];
  const float* b1  = (const float*)d_in[3];
  const float* W2  = (const float*)d_in[4];
  const float* b2  = (const float*)d_in[5];
  const float* Ws1 = (const float*)d_in[6];
  const float* bs1 = (const float*)d_in[7];
  const float* Ws2 = (const float*)d_in[8];
  const float* bs2 = (const float*)d_in[9];
  float* out = (float*)d_out;

  // workspace layout (bytes), ~281.4 MiB total
  char* ws = (char*)d_ws;
  int*      cnt    = (int*)(ws + 0);                 // 16 ints
  int*      base   = (int*)(ws + 64);                // 16 ints
  int*      tok    = (int*)(ws + 256);               // 9*4096 ints
  float*    wof    = (float*)(ws + 256 + 147456);
  int*      rankof = (int*)(ws + 256 + 2 * 147456);
  ushort_t* Xbf    = (ushort_t*)(ws + 442624);       // [4096][1024] bf16
  ushort_t* W1T    = (ushort_t*)(ws + 8831232);      // 8x[4096][1024] bf16, then Ws1T
  ushort_t* Ws1T   = W1T + 8L * ESTRIDE;             // [4096][1024] (pseudo-expert 8)
  ushort_t* W2T    = (ushort_t*)(ws + 84328704);     // 8x[1024][4096] bf16, then Ws2T
  ushort_t* Ws2T   = W2T + 8L * ESTRIDE;
  ushort_t* He     = (ushort_t*)(ws + 159826176);    // 12416 rows x 4096 bf16
  float*    ybuf   = (float*)(ws + 261538048);       // 2 x [4096][1024] fp32
  (void)Ws1T; (void)Ws2T;  // addressed via e*ESTRIDE from W1T/W2T

  hipMemsetAsync(cnt, 0, 64, stream);
  gate_kernel<<<T_TOK, 64, 0, stream>>>(x, Wg, cnt, tok, wof, rankof);
  scan_kernel<<<1, 64, 0, stream>>>(cnt, base);
  cvt_x_kernel<<<2048, 256, 0, stream>>>(x, Xbf);
  tcvt_kernel<<<dim3(64, 16, 8), 256, 0, stream>>>(W1, W1T, 1024, 4096);
  tcvt_kernel<<<dim3(16, 64, 8), 256, 0, stream>>>(W2, W2T, 4096, 1024);
  tcvt_kernel<<<dim3(64, 16, 1), 256, 0, stream>>>(Ws1, W1T + 8L * ESTRIDE, 1024, 4096);
  tcvt_kernel<<<dim3(16, 64, 1), 256, 0, stream>>>(Ws2, W2T + 8L * ESTRIDE, 4096, 1024);
  gemm_kernel<1024, 4096, 1><<<dim3(32, 32, 9), 256, 0, stream>>>(
      Xbf, W1T, b1, bs1, cnt, base, tok, wof, rankof, He, ybuf, out);
  gemm_kernel<4096, 1024, 2><<<dim3(8, 32, 9), 256, 0, stream>>>(
      He, W2T, b2, bs2, cnt, base, tok, wof, rankof, He, ybuf, out);
  final_add_kernel<<<4096, 256, 0, stream>>>(out, ybuf);
}